// Round 1
// baseline (221.425 us; speedup 1.0000x reference)
//
#include <hip/hip_runtime.h>
#include <math.h>

#define H 1024
#define S 32768

__device__ __forceinline__ float wave_reduce_sum(float v) {
    #pragma unroll
    for (int off = 32; off > 0; off >>= 1) v += __shfl_xor(v, off, 64);
    return v;
}

// y[row] = dot(W[row,:], x) + b[row].  One wave per row, 4 rows per 256-thread block.
__global__ __launch_bounds__(256) void gemv_kernel(const float* __restrict__ W,
                                                   const float* __restrict__ x,
                                                   const float* __restrict__ b,
                                                   float* __restrict__ y) {
    __shared__ float xs[H];
    const int tid = threadIdx.x;
    // stage x (1024 floats) into LDS: 256 threads x float4
    reinterpret_cast<float4*>(xs)[tid] = reinterpret_cast<const float4*>(x)[tid];
    __syncthreads();

    const int wave = tid >> 6, lane = tid & 63;
    const int row = blockIdx.x * 4 + wave;
    const float4* Wr = reinterpret_cast<const float4*>(W + (size_t)row * H);
    const float4* xs4 = reinterpret_cast<const float4*>(xs);

    float acc = 0.f;
    #pragma unroll
    for (int k = 0; k < 4; ++k) {
        const int idx = k * 64 + lane;        // 256 float4 per row, coalesced
        const float4 w = Wr[idx];
        const float4 e = xs4[idx];
        acc += w.x * e.x + w.y * e.y + w.z * e.z + w.w * e.w;
    }
    acc = wave_reduce_sum(acc);
    if (lane == 0) y[row] = acc + b[row];
}

// scores[row] = dot(enc[row,:], energy); also emit per-block max for softmax.
__global__ __launch_bounds__(256) void scores_kernel(const float* __restrict__ enc,
                                                     const float* __restrict__ energy,
                                                     float* __restrict__ scores,
                                                     float* __restrict__ blockmax) {
    __shared__ float es[H];
    __shared__ float smax[4];
    const int tid = threadIdx.x;
    reinterpret_cast<float4*>(es)[tid] = reinterpret_cast<const float4*>(energy)[tid];
    __syncthreads();

    const int wave = tid >> 6, lane = tid & 63;
    const int row = blockIdx.x * 4 + wave;
    const float4* Er = reinterpret_cast<const float4*>(enc + (size_t)row * H);
    const float4* es4 = reinterpret_cast<const float4*>(es);

    float acc = 0.f;
    #pragma unroll
    for (int k = 0; k < 4; ++k) {
        const int idx = k * 64 + lane;
        const float4 w = Er[idx];
        const float4 e = es4[idx];
        acc += w.x * e.x + w.y * e.y + w.z * e.z + w.w * e.w;
    }
    acc = wave_reduce_sum(acc);
    if (lane == 0) { scores[row] = acc; smax[wave] = acc; }
    __syncthreads();
    if (tid == 0) {
        blockmax[blockIdx.x] = fmaxf(fmaxf(smax[0], smax[1]), fmaxf(smax[2], smax[3]));
    }
}

// Single block: global max over blockmax[], then sum of exp(scores - max).
__global__ __launch_bounds__(1024) void softmax_reduce_kernel(const float* __restrict__ scores,
                                                              const float* __restrict__ blockmax,
                                                              int nbm,
                                                              float* __restrict__ stats) {
    __shared__ float red[1024];
    const int tid = threadIdx.x;

    float m = -INFINITY;
    for (int i = tid; i < nbm; i += 1024) m = fmaxf(m, blockmax[i]);
    red[tid] = m;
    __syncthreads();
    for (int s = 512; s > 0; s >>= 1) {
        if (tid < s) red[tid] = fmaxf(red[tid], red[tid + s]);
        __syncthreads();
    }
    m = red[0];
    __syncthreads();

    float sum = 0.f;
    for (int i = tid; i < S; i += 1024) sum += expf(scores[i] - m);
    red[tid] = sum;
    __syncthreads();
    for (int s = 512; s > 0; s >>= 1) {
        if (tid < s) red[tid] += red[tid + s];
        __syncthreads();
    }
    if (tid == 0) { stats[0] = m; stats[1] = 1.0f / red[0]; }
}

__global__ __launch_bounds__(256) void normalize_kernel(const float* __restrict__ scores,
                                                        const float* __restrict__ stats,
                                                        float* __restrict__ out) {
    const int i = blockIdx.x * 256 + threadIdx.x;
    const float m = stats[0], inv = stats[1];
    out[i] = expf(scores[i] - m) * inv;
}

extern "C" void kernel_launch(void* const* d_in, const int* in_sizes, int n_in,
                              void* d_out, int out_size, void* d_ws, size_t ws_size,
                              hipStream_t stream) {
    const float* hidden = (const float*)d_in[0];
    const float* enc    = (const float*)d_in[1];
    const float* W_lin  = (const float*)d_in[2];
    const float* b_lin  = (const float*)d_in[3];
    const float* W_attn = (const float*)d_in[4];
    const float* b_attn = (const float*)d_in[5];
    float* out = (float*)d_out;
    float* ws  = (float*)d_ws;

    // workspace layout (floats, all 16B-aligned offsets)
    float* scores   = ws;                  // S      = 32768
    float* blockmax = ws + S;              // 8192
    float* h        = ws + S + 8192;       // 1024
    float* energy   = ws + S + 8192 + H;   // 1024
    float* stats    = ws + S + 8192 + 2*H; // 2

    const int nblk_scores = S / 4;         // 8192 blocks, 4 rows each

    gemv_kernel<<<H / 4, 256, 0, stream>>>(W_lin, hidden, b_lin, h);
    gemv_kernel<<<H / 4, 256, 0, stream>>>(W_attn, h, b_attn, energy);
    scores_kernel<<<nblk_scores, 256, 0, stream>>>(enc, energy, scores, blockmax);
    softmax_reduce_kernel<<<1, 1024, 0, stream>>>(scores, blockmax, nblk_scores, stats);
    normalize_kernel<<<S / 256, 256, 0, stream>>>(scores, stats, out);
}